// Round 1
// baseline (1399.161 us; speedup 1.0000x reference)
//
#include <hip/hip_runtime.h>
#include <stdint.h>

typedef unsigned short u16;
typedef __bf16 bf16x8 __attribute__((ext_vector_type(8)));
typedef float f32x4 __attribute__((ext_vector_type(4)));

#define AS1 __attribute__((address_space(1)))
#define AS3 __attribute__((address_space(3)))

__device__ __forceinline__ void g2l16(const void* g, void* l) {
  __builtin_amdgcn_global_load_lds((AS1 void*)(void*)g, (AS3 void*)l, 16, 0, 0);
}

__device__ __forceinline__ u16 f2bf(float f) {
  union { float f; uint32_t u; } v; v.f = f;
  return (u16)((v.u + 0x7fffu + ((v.u >> 16) & 1u)) >> 16);
}
__device__ __forceinline__ float bf2f(u16 b) {
  union { uint32_t u; float f; } v; v.u = ((uint32_t)b) << 16;
  return v.f;
}

// ---- top-2 expert selection per batch (B=4, E=8) ----
__global__ void k_top2(const float* __restrict__ gv, int* __restrict__ idx) {
  int b = threadIdx.x;
  if (b < 4) {
    const float* g = gv + b * 8;
    int i1 = 0; float v1 = g[0];
    for (int e = 1; e < 8; ++e) if (g[e] > v1) { v1 = g[e]; i1 = e; }
    int i2 = -1; float v2 = -3.0e38f;
    for (int e = 0; e < 8; ++e) if (e != i1 && g[e] > v2) { v2 = g[e]; i2 = e; }
    idx[2 * b] = i1; idx[2 * b + 1] = i2;
  }
}

// ---- fp32 -> bf16 cast, vectorized ----
__global__ void k_cast(const float* __restrict__ in, u16* __restrict__ out, int n4) {
  int i = blockIdx.x * 256 + threadIdx.x;
  if (i < n4) {
    float4 v = ((const float4*)in)[i];
    ushort4 o = make_ushort4(f2bf(v.x), f2bf(v.y), f2bf(v.z), f2bf(v.w));
    ((ushort4*)out)[i] = o;
  }
}

// ---- xa[bs][0:32] = LORA_SCALE * x[bs] @ A_cat  for gate(0:32 of o<32) and up ----
__global__ __launch_bounds__(512) void k_xa(const float* __restrict__ x,
    const float* __restrict__ Ag, const float* __restrict__ Au,
    const int* __restrict__ idx, u16* __restrict__ xag, u16* __restrict__ xau) {
  __shared__ float xr[2048];
  __shared__ float part[512];
  int bs = blockIdx.x, b = bs >> 11, tid = threadIdx.x;
  ((float4*)xr)[tid] = ((const float4*)(x + (size_t)bs * 2048))[tid];
  __syncthreads();
  int o = tid & 63, seg = tid >> 6;       // 8 segments of 256
  int which = o >> 5, j = o & 31;
  int e = (j & 16) ? idx[2 * b + 1] : idx[2 * b];
  int r = j & 15;
  const float* A = (which ? Au : Ag) + ((size_t)e * 2048) * 16 + r;
  float s = 0.f;
  int h0 = seg * 256;
  #pragma unroll 4
  for (int h = h0; h < h0 + 256; ++h) s += xr[h] * A[(size_t)h * 16];
  part[tid] = s;
  __syncthreads();
  if (tid < 64) {
    float t = 0.f;
    #pragma unroll
    for (int k = 0; k < 8; ++k) t += part[k * 64 + o];
    (which ? xau : xag)[(size_t)bs * 32 + j] = f2bf(2.0f * t);  // LORA_SCALE=2
  }
}

// ---- ha[bs][0:32] = LORA_SCALE * h[bs] @ Ad_cat (h is bf16, row len 5504) ----
__global__ __launch_bounds__(512) void k_ha(const u16* __restrict__ h,
    const float* __restrict__ Ad, const int* __restrict__ idx, u16* __restrict__ ha) {
  __shared__ float hr[5504];
  __shared__ float part[512];
  int bs = blockIdx.x, b = bs >> 11, tid = threadIdx.x;
  const u16* hrow = h + (size_t)bs * 5504;
  for (int i = tid; i < 1376; i += 512) {
    ushort4 v = ((const ushort4*)hrow)[i];
    hr[4 * i + 0] = bf2f(v.x); hr[4 * i + 1] = bf2f(v.y);
    hr[4 * i + 2] = bf2f(v.z); hr[4 * i + 3] = bf2f(v.w);
  }
  __syncthreads();
  int j = tid & 31, seg = tid >> 5;       // 16 segments of 344
  int e = (j & 16) ? idx[2 * b + 1] : idx[2 * b];
  int r = j & 15;
  const float* A = Ad + ((size_t)e * 5504) * 16 + r;
  float s = 0.f;
  int h0 = seg * 344;
  #pragma unroll 4
  for (int i = h0; i < h0 + 344; ++i) s += hr[i] * A[(size_t)i * 16];
  part[tid] = s;
  __syncthreads();
  if (tid < 32) {
    float t = 0.f;
    #pragma unroll
    for (int k = 0; k < 16; ++k) t += part[k * 32 + j];
    ha[(size_t)bs * 32 + j] = f2bf(2.0f * t);
  }
}

// ---- build per-batch B_cat^T: out[b][n][j] = B[e(b, j>=16)][j&15][n], bf16 ----
__global__ void k_bT(const float* __restrict__ Bsrc, const int* __restrict__ idx,
                     u16* __restrict__ out, int N) {
  int t = blockIdx.x * 256 + threadIdx.x;
  if (t < 4 * N * 32) {
    int j = t & 31;
    int n = (t >> 5) % N;
    int b = t / (N * 32);
    int e = (j & 16) ? idx[2 * b + 1] : idx[2 * b];
    int r = j & 15;
    out[t] = f2bf(Bsrc[((size_t)e * 16 + r) * N + n]);
  }
}

// ---- main GEMM: C[m,n] = sum_k A[m,k]*Bm[n,k] + sum_{j<32} A2[m,j]*B2[batch][n,j]
// mode 0: store silu(C) as bf16  (gate)
// mode 1: store bf16( Gprev[pos] * C )  (up, fused SwiGLU; in-place over Gprev)
// mode 2: store fp32 C  (down)
// 128x128 tile, BK=64, 256 threads / 4 waves, each wave a 64x64 quadrant,
// XOR-swizzled LDS chunk layout for global_load_lds + conflict-light ds_read_b128.
__global__ __launch_bounds__(256, 3)
void k_gemm(const u16* __restrict__ A, const u16* __restrict__ Bm,
            const u16* __restrict__ A2, const u16* __restrict__ B2,
            const u16* Gprev, void* Out,
            int N, int K, int mode) {
  __shared__ u16 sA[128 * 64];
  __shared__ u16 sB[128 * 64];
  int nt = N >> 7;
  int bm = blockIdx.x / nt, bn = blockIdx.x % nt;
  int m0 = bm << 7, n0 = bn << 7;
  int tid = threadIdx.x, lane = tid & 63, w = tid >> 6;
  int mo = (w & 1) << 6, no = (w >> 1) << 6;

  // staging addresses: wave w handles chunk-blocks 4w..4w+3 (64 chunks each)
  const u16* ga[4]; const u16* gb[4];
  u16* la[4]; u16* lb[4];
  #pragma unroll
  for (int t = 0; t < 4; ++t) {
    int cb = 4 * w + t;
    int q = cb * 64 + lane;
    int row = q >> 3;
    int c = (q & 7) ^ (row & 7);              // source chunk for this slot
    ga[t] = A + (size_t)(m0 + row) * K + c * 8;
    gb[t] = Bm + (size_t)(n0 + row) * K + c * 8;
    la[t] = sA + cb * 512;                    // wave-uniform LDS base
    lb[t] = sB + cb * 512;
  }

  f32x4 acc[4][4] = {};

  int kiters = K >> 6;
  for (int kt = 0; kt < kiters; ++kt) {
    #pragma unroll
    for (int t = 0; t < 4; ++t) { g2l16(ga[t], la[t]); ga[t] += 64; }
    #pragma unroll
    for (int t = 0; t < 4; ++t) { g2l16(gb[t], lb[t]); gb[t] += 64; }
    __syncthreads();
    #pragma unroll
    for (int ks = 0; ks < 2; ++ks) {
      bf16x8 af[4], bfr[4];
      int cb0 = ks * 4 + (lane >> 4);
      #pragma unroll
      for (int mi = 0; mi < 4; ++mi) {
        int row = mo + mi * 16 + (lane & 15);
        af[mi] = *(const bf16x8*)(sA + (row * 8 + (cb0 ^ (row & 7))) * 8);
      }
      #pragma unroll
      for (int ni = 0; ni < 4; ++ni) {
        int row = no + ni * 16 + (lane & 15);
        bfr[ni] = *(const bf16x8*)(sB + (row * 8 + (cb0 ^ (row & 7))) * 8);
      }
      #pragma unroll
      for (int mi = 0; mi < 4; ++mi)
        #pragma unroll
        for (int ni = 0; ni < 4; ++ni)
          acc[mi][ni] = __builtin_amdgcn_mfma_f32_16x16x32_bf16(
              af[mi], bfr[ni], acc[mi][ni], 0, 0, 0);
    }
    __syncthreads();
  }

  // ---- LoRA extra K=32 step: rows have 4 chunks, swizzle with (row&3) ----
  {
    int batch = m0 >> 11;
    const u16* B2b = B2 + (size_t)batch * N * 32;
    #pragma unroll
    for (int t = 0; t < 2; ++t) {
      int cb = 2 * w + t;
      int q = cb * 64 + lane;
      int row = q >> 2;
      int c = (q & 3) ^ (row & 3);
      g2l16(A2 + (size_t)(m0 + row) * 32 + c * 8, sA + cb * 512);
      g2l16(B2b + (size_t)(n0 + row) * 32 + c * 8, sB + cb * 512);
    }
    __syncthreads();
    bf16x8 af[4], bfr[4];
    int c0 = lane >> 4;
    #pragma unroll
    for (int mi = 0; mi < 4; ++mi) {
      int row = mo + mi * 16 + (lane & 15);
      af[mi] = *(const bf16x8*)(sA + (row * 4 + (c0 ^ (row & 3))) * 8);
    }
    #pragma unroll
    for (int ni = 0; ni < 4; ++ni) {
      int row = no + ni * 16 + (lane & 15);
      bfr[ni] = *(const bf16x8*)(sB + (row * 4 + (c0 ^ (row & 3))) * 8);
    }
    #pragma unroll
    for (int mi = 0; mi < 4; ++mi)
      #pragma unroll
      for (int ni = 0; ni < 4; ++ni)
        acc[mi][ni] = __builtin_amdgcn_mfma_f32_16x16x32_bf16(
            af[mi], bfr[ni], acc[mi][ni], 0, 0, 0);
  }

  // ---- epilogue; C layout: col = lane&15, row = (lane>>4)*4 + reg ----
  int rb = (lane >> 4) * 4;
  int cc = lane & 15;
  #pragma unroll
  for (int mi = 0; mi < 4; ++mi) {
    #pragma unroll
    for (int ni = 0; ni < 4; ++ni) {
      #pragma unroll
      for (int reg = 0; reg < 4; ++reg) {
        int gr = m0 + mo + mi * 16 + rb + reg;
        int gc = n0 + no + ni * 16 + cc;
        size_t pos = (size_t)gr * N + gc;
        float v = acc[mi][ni][reg];
        if (mode == 0) {
          v = v / (1.f + __expf(-v));               // silu
          ((u16*)Out)[pos] = f2bf(v);
        } else if (mode == 1) {
          float g = bf2f(Gprev[pos]);               // silu(gate), read-then-write in place
          ((u16*)Out)[pos] = f2bf(g * v);
        } else {
          ((float*)Out)[pos] = v;
        }
      }
    }
  }
}

extern "C" void kernel_launch(void* const* d_in, const int* in_sizes, int n_in,
                              void* d_out, int out_size, void* d_ws, size_t ws_size,
                              hipStream_t stream) {
  const float* x  = (const float*)d_in[0];
  const float* gv = (const float*)d_in[1];
  const float* Wg = (const float*)d_in[2];
  const float* Ag = (const float*)d_in[3];
  const float* Bg = (const float*)d_in[4];
  const float* Wu = (const float*)d_in[5];
  const float* Au = (const float*)d_in[6];
  const float* Bu = (const float*)d_in[7];
  const float* Wd = (const float*)d_in[8];
  const float* Ad = (const float*)d_in[9];
  const float* Bd = (const float*)d_in[10];
  float* out = (float*)d_out;

  char* ws = (char*)d_ws;
  size_t off = 0;
  auto alloc = [&](size_t bytes) -> void* {
    void* p = ws + off;
    off = (off + bytes + 255) & ~(size_t)255;
    return p;
  };
  int* idx  = (int*)alloc(32);
  u16* xb   = (u16*)alloc((size_t)8192 * 2048 * 2);
  u16* Wgb  = (u16*)alloc((size_t)5504 * 2048 * 2);
  u16* Wub  = (u16*)alloc((size_t)5504 * 2048 * 2);
  u16* Wdb  = (u16*)alloc((size_t)2048 * 5504 * 2);
  u16* xag  = (u16*)alloc((size_t)8192 * 32 * 2);
  u16* xau  = (u16*)alloc((size_t)8192 * 32 * 2);
  u16* ha   = (u16*)alloc((size_t)8192 * 32 * 2);
  u16* BgT  = (u16*)alloc((size_t)4 * 5504 * 32 * 2);
  u16* BuT  = (u16*)alloc((size_t)4 * 5504 * 32 * 2);
  u16* BdT  = (u16*)alloc((size_t)4 * 2048 * 32 * 2);
  u16* gbuf = (u16*)alloc((size_t)8192 * 5504 * 2);  // silu(gate), then h in-place
  if (off > ws_size) return;  // workspace too small -> fail loudly (wrong output)

  k_top2<<<1, 64, 0, stream>>>(gv, idx);
  k_cast<<<16384, 256, 0, stream>>>(x, xb, 4194304);         // 8192x2048
  k_cast<<<11008, 256, 0, stream>>>(Wg, Wgb, 2818048);       // 5504x2048
  k_cast<<<11008, 256, 0, stream>>>(Wu, Wub, 2818048);
  k_cast<<<11008, 256, 0, stream>>>(Wd, Wdb, 2818048);       // 2048x5504
  k_xa<<<8192, 512, 0, stream>>>(x, Ag, Au, idx, xag, xau);
  k_bT<<<2752, 256, 0, stream>>>(Bg, idx, BgT, 5504);
  k_bT<<<2752, 256, 0, stream>>>(Bu, idx, BuT, 5504);
  k_bT<<<1024, 256, 0, stream>>>(Bd, idx, BdT, 2048);

  // gate: silu(x@Wg^T + lora) -> gbuf (bf16)
  k_gemm<<<64 * 43, 256, 0, stream>>>(xb, Wgb, xag, BgT, (const u16*)nullptr,
                                      gbuf, 5504, 2048, 0);
  // up: h = silu_gate * (x@Wu^T + lora) -> gbuf in place
  k_gemm<<<64 * 43, 256, 0, stream>>>(xb, Wub, xau, BuT, gbuf, gbuf, 5504, 2048, 1);
  // ha = scale * h @ Ad_cat
  k_ha<<<8192, 512, 0, stream>>>(gbuf, Ad, idx, ha);
  // down: out = h@Wd^T + lora (fp32)
  k_gemm<<<64 * 16, 256, 0, stream>>>(gbuf, Wdb, ha, BdT, (const u16*)nullptr,
                                      out, 2048, 5504, 2);
}

// Round 2
// 1013.110 us; speedup vs baseline: 1.3811x; 1.3811x over previous
//
#include <hip/hip_runtime.h>
#include <stdint.h>

typedef unsigned short u16;
typedef __bf16 bf16x8 __attribute__((ext_vector_type(8)));
typedef float f32x4 __attribute__((ext_vector_type(4)));

#define AS1 __attribute__((address_space(1)))
#define AS3 __attribute__((address_space(3)))

__device__ __forceinline__ void g2l16(const void* g, void* l) {
  __builtin_amdgcn_global_load_lds((AS1 void*)(void*)g, (AS3 void*)l, 16, 0, 0);
}

__device__ __forceinline__ u16 f2bf(float f) {
  union { float f; uint32_t u; } v; v.f = f;
  return (u16)((v.u + 0x7fffu + ((v.u >> 16) & 1u)) >> 16);
}
__device__ __forceinline__ float bf2f(u16 b) {
  union { uint32_t u; float f; } v; v.u = ((uint32_t)b) << 16;
  return v.f;
}

// ---- top-2 expert selection per batch (B=4, E=8) ----
__global__ void k_top2(const float* __restrict__ gv, int* __restrict__ idx) {
  int b = threadIdx.x;
  if (b < 4) {
    const float* g = gv + b * 8;
    int i1 = 0; float v1 = g[0];
    for (int e = 1; e < 8; ++e) if (g[e] > v1) { v1 = g[e]; i1 = e; }
    int i2 = -1; float v2 = -3.0e38f;
    for (int e = 0; e < 8; ++e) if (e != i1 && g[e] > v2) { v2 = g[e]; i2 = e; }
    idx[2 * b] = i1; idx[2 * b + 1] = i2;
  }
}

// ---- fp32 -> bf16 cast, vectorized ----
__global__ void k_cast(const float* __restrict__ in, u16* __restrict__ out, int n4) {
  int i = blockIdx.x * 256 + threadIdx.x;
  if (i < n4) {
    float4 v = ((const float4*)in)[i];
    ushort4 o = make_ushort4(f2bf(v.x), f2bf(v.y), f2bf(v.z), f2bf(v.w));
    ((ushort4*)out)[i] = o;
  }
}

// ---- per-batch A^T panels: out[b][j][k] = src[e][k][r], bf16 ----
// jmax=64: j>=32 pulls from A1 (up), else A0 (gate). jmax=32: all from A0.
__global__ void k_aT(const float* __restrict__ A0, const float* __restrict__ A1,
                     const int* __restrict__ idx, u16* __restrict__ out,
                     int Kd, int jmax) {
  int t = blockIdx.x * 256 + threadIdx.x;
  if (t >= 4 * jmax * Kd) return;
  int h = t % Kd;
  int j = (t / Kd) % jmax;
  int b = t / (Kd * jmax);
  const float* src = (j >= 32) ? A1 : A0;
  int jj = j & 31;
  int e = idx[2 * b + ((jj >> 4) & 1)];
  int r = jj & 15;
  out[t] = f2bf(src[((size_t)e * Kd + h) * 16 + r]);
}

// ---- build per-batch B_cat^T: out[b][n][j] = B[e(b, j>=16)][j&15][n], bf16 ----
__global__ void k_bT(const float* __restrict__ Bsrc, const int* __restrict__ idx,
                     u16* __restrict__ out, int N) {
  int t = blockIdx.x * 256 + threadIdx.x;
  if (t < 4 * N * 32) {
    int j = t & 31;
    int n = (t >> 5) % N;
    int b = t / (N * 32);
    int e = (j & 16) ? idx[2 * b + 1] : idx[2 * b];
    int r = j & 15;
    out[t] = f2bf(Bsrc[((size_t)e * 16 + r) * N + n]);
  }
}

// ---- skinny MFMA GEMM with split-K:
// part[chunk][m][j] = sum_{k in chunk} A[m,k] * BT[batch(m)][j,k]
// 128-row m-tile, N2 columns (32 or 64), BK=64, 4 waves (32 rows each).
template <int N2>
__global__ __launch_bounds__(256) void k_skinny(
    const u16* __restrict__ A, const u16* __restrict__ BT,
    float* __restrict__ part, int M, int K, int total_iters, int iters_per_chunk) {
  __shared__ u16 sA[128 * 64];
  __shared__ u16 sB[N2 * 64];
  int nm = M >> 7;
  int bm = blockIdx.x % nm, chunk = blockIdx.x / nm;
  int m0 = bm << 7;
  int batch = m0 >> 11;
  int tid = threadIdx.x, lane = tid & 63, w = tid >> 6;
  int kb = chunk * iters_per_chunk;
  int ke = min(total_iters, kb + iters_per_chunk);

  const u16* Bb = BT + (size_t)batch * N2 * K;

  const u16* ga[4]; u16* la[4];
  #pragma unroll
  for (int t = 0; t < 4; ++t) {
    int cb = 4 * w + t;
    int q = cb * 64 + lane;
    int row = q >> 3;
    int c = (q & 7) ^ (row & 7);
    ga[t] = A + (size_t)(m0 + row) * K + (size_t)kb * 64 + c * 8;
    la[t] = sA + cb * 512;
  }
  constexpr int nB = N2 / 32;  // chunk-blocks per wave for B (64->2, 32->1)
  const u16* gb[nB]; u16* lb[nB];
  #pragma unroll
  for (int t = 0; t < nB; ++t) {
    int cb = nB * w + t;
    int q = cb * 64 + lane;
    int row = q >> 3;
    int c = (q & 7) ^ (row & 7);
    gb[t] = Bb + (size_t)row * K + (size_t)kb * 64 + c * 8;
    lb[t] = sB + cb * 512;
  }

  f32x4 acc[2][N2 / 16] = {};
  for (int kt = kb; kt < ke; ++kt) {
    #pragma unroll
    for (int t = 0; t < 4; ++t) { g2l16(ga[t], la[t]); ga[t] += 64; }
    #pragma unroll
    for (int t = 0; t < nB; ++t) { g2l16(gb[t], lb[t]); gb[t] += 64; }
    __syncthreads();
    #pragma unroll
    for (int ks = 0; ks < 2; ++ks) {
      int cb0 = ks * 4 + (lane >> 4);
      bf16x8 af[2], bfr[N2 / 16];
      #pragma unroll
      for (int mi = 0; mi < 2; ++mi) {
        int row = 32 * w + mi * 16 + (lane & 15);
        af[mi] = *(const bf16x8*)(sA + (row * 8 + (cb0 ^ (row & 7))) * 8);
      }
      #pragma unroll
      for (int ni = 0; ni < N2 / 16; ++ni) {
        int row = ni * 16 + (lane & 15);
        bfr[ni] = *(const bf16x8*)(sB + (row * 8 + (cb0 ^ (row & 7))) * 8);
      }
      #pragma unroll
      for (int mi = 0; mi < 2; ++mi)
        #pragma unroll
        for (int ni = 0; ni < N2 / 16; ++ni)
          acc[mi][ni] = __builtin_amdgcn_mfma_f32_16x16x32_bf16(
              af[mi], bfr[ni], acc[mi][ni], 0, 0, 0);
    }
    __syncthreads();
  }

  int rb = (lane >> 4) * 4, cc = lane & 15;
  #pragma unroll
  for (int mi = 0; mi < 2; ++mi)
    #pragma unroll
    for (int ni = 0; ni < N2 / 16; ++ni)
      #pragma unroll
      for (int reg = 0; reg < 4; ++reg) {
        int gr = m0 + 32 * w + mi * 16 + rb + reg;
        int gc = ni * 16 + cc;
        part[((size_t)chunk * M + gr) * N2 + gc] = acc[mi][ni][reg];
      }
}

// ---- finalize split-K: out = bf16(2 * sum_chunks part) ----
__global__ void k_fin(const float* __restrict__ part, u16* __restrict__ out0,
                      u16* __restrict__ out1, int M, int N2, int nch) {
  int t = blockIdx.x * 256 + threadIdx.x;
  if (t >= M * N2) return;
  float s = 0.f;
  for (int c = 0; c < nch; ++c) s += part[(size_t)c * M * N2 + t];
  int j = t % N2, bs = t / N2;
  u16 v = f2bf(2.0f * s);  // LORA_SCALE = 2
  if (N2 == 64) {
    if (j < 32) out0[(size_t)bs * 32 + j] = v;
    else        out1[(size_t)bs * 32 + (j - 32)] = v;
  } else {
    out0[(size_t)bs * 32 + j] = v;
  }
}

// ---- main GEMM: C[m,n] = sum_k A[m,k]*Bm[n,k] + sum_{j<32} A2[m,j]*B2[batch][n,j]
// mode 0: store silu(C) bf16 (gate); mode 1: store bf16(Gprev*C) (up, in-place);
// mode 2: store fp32 C (down)
__global__ __launch_bounds__(256, 3)
void k_gemm(const u16* __restrict__ A, const u16* __restrict__ Bm,
            const u16* __restrict__ A2, const u16* __restrict__ B2,
            const u16* Gprev, void* Out,
            int N, int K, int mode) {
  __shared__ u16 sA[128 * 64];
  __shared__ u16 sB[128 * 64];
  int nt = N >> 7;
  int bm = blockIdx.x / nt, bn = blockIdx.x % nt;
  int m0 = bm << 7, n0 = bn << 7;
  int tid = threadIdx.x, lane = tid & 63, w = tid >> 6;
  int mo = (w & 1) << 6, no = (w >> 1) << 6;

  const u16* ga[4]; const u16* gb[4];
  u16* la[4]; u16* lb[4];
  #pragma unroll
  for (int t = 0; t < 4; ++t) {
    int cb = 4 * w + t;
    int q = cb * 64 + lane;
    int row = q >> 3;
    int c = (q & 7) ^ (row & 7);
    ga[t] = A + (size_t)(m0 + row) * K + c * 8;
    gb[t] = Bm + (size_t)(n0 + row) * K + c * 8;
    la[t] = sA + cb * 512;
    lb[t] = sB + cb * 512;
  }

  f32x4 acc[4][4] = {};

  int kiters = K >> 6;
  for (int kt = 0; kt < kiters; ++kt) {
    #pragma unroll
    for (int t = 0; t < 4; ++t) { g2l16(ga[t], la[t]); ga[t] += 64; }
    #pragma unroll
    for (int t = 0; t < 4; ++t) { g2l16(gb[t], lb[t]); gb[t] += 64; }
    __syncthreads();
    #pragma unroll
    for (int ks = 0; ks < 2; ++ks) {
      bf16x8 af[4], bfr[4];
      int cb0 = ks * 4 + (lane >> 4);
      #pragma unroll
      for (int mi = 0; mi < 4; ++mi) {
        int row = mo + mi * 16 + (lane & 15);
        af[mi] = *(const bf16x8*)(sA + (row * 8 + (cb0 ^ (row & 7))) * 8);
      }
      #pragma unroll
      for (int ni = 0; ni < 4; ++ni) {
        int row = no + ni * 16 + (lane & 15);
        bfr[ni] = *(const bf16x8*)(sB + (row * 8 + (cb0 ^ (row & 7))) * 8);
      }
      #pragma unroll
      for (int mi = 0; mi < 4; ++mi)
        #pragma unroll
        for (int ni = 0; ni < 4; ++ni)
          acc[mi][ni] = __builtin_amdgcn_mfma_f32_16x16x32_bf16(
              af[mi], bfr[ni], acc[mi][ni], 0, 0, 0);
    }
    __syncthreads();
  }

  // LoRA extra K=32 step
  {
    int batch = m0 >> 11;
    const u16* B2b = B2 + (size_t)batch * N * 32;
    #pragma unroll
    for (int t = 0; t < 2; ++t) {
      int cb = 2 * w + t;
      int q = cb * 64 + lane;
      int row = q >> 2;
      int c = (q & 3) ^ (row & 3);
      g2l16(A2 + (size_t)(m0 + row) * 32 + c * 8, sA + cb * 512);
      g2l16(B2b + (size_t)(n0 + row) * 32 + c * 8, sB + cb * 512);
    }
    __syncthreads();
    bf16x8 af[4], bfr[4];
    int c0 = lane >> 4;
    #pragma unroll
    for (int mi = 0; mi < 4; ++mi) {
      int row = mo + mi * 16 + (lane & 15);
      af[mi] = *(const bf16x8*)(sA + (row * 4 + (c0 ^ (row & 3))) * 8);
    }
    #pragma unroll
    for (int ni = 0; ni < 4; ++ni) {
      int row = no + ni * 16 + (lane & 15);
      bfr[ni] = *(const bf16x8*)(sB + (row * 4 + (c0 ^ (row & 3))) * 8);
    }
    #pragma unroll
    for (int mi = 0; mi < 4; ++mi)
      #pragma unroll
      for (int ni = 0; ni < 4; ++ni)
        acc[mi][ni] = __builtin_amdgcn_mfma_f32_16x16x32_bf16(
            af[mi], bfr[ni], acc[mi][ni], 0, 0, 0);
  }

  int rb = (lane >> 4) * 4;
  int cc = lane & 15;
  #pragma unroll
  for (int mi = 0; mi < 4; ++mi) {
    #pragma unroll
    for (int ni = 0; ni < 4; ++ni) {
      #pragma unroll
      for (int reg = 0; reg < 4; ++reg) {
        int gr = m0 + mo + mi * 16 + rb + reg;
        int gc = n0 + no + ni * 16 + cc;
        size_t pos = (size_t)gr * N + gc;
        float v = acc[mi][ni][reg];
        if (mode == 0) {
          v = v / (1.f + __expf(-v));
          ((u16*)Out)[pos] = f2bf(v);
        } else if (mode == 1) {
          float g = bf2f(Gprev[pos]);
          ((u16*)Out)[pos] = f2bf(g * v);
        } else {
          ((float*)Out)[pos] = v;
        }
      }
    }
  }
}

extern "C" void kernel_launch(void* const* d_in, const int* in_sizes, int n_in,
                              void* d_out, int out_size, void* d_ws, size_t ws_size,
                              hipStream_t stream) {
  const float* x  = (const float*)d_in[0];
  const float* gv = (const float*)d_in[1];
  const float* Wg = (const float*)d_in[2];
  const float* Ag = (const float*)d_in[3];
  const float* Bg = (const float*)d_in[4];
  const float* Wu = (const float*)d_in[5];
  const float* Au = (const float*)d_in[6];
  const float* Bu = (const float*)d_in[7];
  const float* Wd = (const float*)d_in[8];
  const float* Ad = (const float*)d_in[9];
  const float* Bd = (const float*)d_in[10];
  float* out = (float*)d_out;

  char* ws = (char*)d_ws;
  size_t off = 0;
  auto alloc = [&](size_t bytes) -> void* {
    void* p = ws + off;
    off = (off + bytes + 255) & ~(size_t)255;
    return p;
  };
  int* idx  = (int*)alloc(32);
  u16* xb   = (u16*)alloc((size_t)8192 * 2048 * 2);
  u16* Wgb  = (u16*)alloc((size_t)5504 * 2048 * 2);
  u16* Wub  = (u16*)alloc((size_t)5504 * 2048 * 2);
  u16* Wdb  = (u16*)alloc((size_t)2048 * 5504 * 2);
  u16* xag  = (u16*)alloc((size_t)8192 * 32 * 2);
  u16* xau  = (u16*)alloc((size_t)8192 * 32 * 2);
  u16* ha   = (u16*)alloc((size_t)8192 * 32 * 2);
  u16* BgT  = (u16*)alloc((size_t)4 * 5504 * 32 * 2);
  u16* BuT  = (u16*)alloc((size_t)4 * 5504 * 32 * 2);
  u16* BdT  = (u16*)alloc((size_t)4 * 2048 * 32 * 2);
  u16* AxT  = (u16*)alloc((size_t)4 * 64 * 2048 * 2);
  u16* AdT  = (u16*)alloc((size_t)4 * 32 * 5504 * 2);
  u16* gbuf = (u16*)alloc((size_t)8192 * 5504 * 2);  // silu(gate), then h in-place
  if (off > ws_size) return;

  // split-K partials aliased onto regions that are dead at their use time:
  // part_xa lives in gbuf (gbuf first written by gate GEMM, after fin_xa)
  // part_ha lives in Wgb (Wgb dead after gate GEMM; part_ha used after up GEMM)
  float* part_xa = (float*)gbuf;   // 4 * 8192 * 64 * 4B = 8 MB  (gbuf is 90 MB)
  float* part_ha = (float*)Wgb;    // 4 * 8192 * 32 * 4B = 4 MB  (Wgb is 22.5 MB)

  k_top2<<<1, 64, 0, stream>>>(gv, idx);
  k_cast<<<16384, 256, 0, stream>>>(x, xb, 4194304);
  k_cast<<<11008, 256, 0, stream>>>(Wg, Wgb, 2818048);
  k_cast<<<11008, 256, 0, stream>>>(Wu, Wub, 2818048);
  k_cast<<<11008, 256, 0, stream>>>(Wd, Wdb, 2818048);
  k_aT<<<2048, 256, 0, stream>>>(Ag, Au, idx, AxT, 2048, 64);
  k_aT<<<2752, 256, 0, stream>>>(Ad, Ad, idx, AdT, 5504, 32);
  k_bT<<<2752, 256, 0, stream>>>(Bg, idx, BgT, 5504);
  k_bT<<<2752, 256, 0, stream>>>(Bu, idx, BuT, 5504);
  k_bT<<<1024, 256, 0, stream>>>(Bd, idx, BdT, 2048);

  // xa: [8192 x 64] = xb @ AxT^T, split-K 4 chunks of 8 BK-iters (K=2048)
  k_skinny<64><<<64 * 4, 256, 0, stream>>>(xb, AxT, part_xa, 8192, 2048, 32, 8);
  k_fin<<<2048, 256, 0, stream>>>(part_xa, xag, xau, 8192, 64, 4);

  // gate: silu(x@Wg^T + lora) -> gbuf (bf16)
  k_gemm<<<64 * 43, 256, 0, stream>>>(xb, Wgb, xag, BgT, (const u16*)nullptr,
                                      gbuf, 5504, 2048, 0);
  // up: h = silu_gate * (x@Wu^T + lora) -> gbuf in place
  k_gemm<<<64 * 43, 256, 0, stream>>>(xb, Wub, xau, BuT, gbuf, gbuf, 5504, 2048, 1);

  // ha: [8192 x 32] = h @ AdT^T, split-K 4 chunks of 22 BK-iters (K=5504, 86 iters)
  k_skinny<32><<<64 * 4, 256, 0, stream>>>(gbuf, AdT, part_ha, 8192, 5504, 86, 22);
  k_fin<<<1024, 256, 0, stream>>>(part_ha, ha, ha, 8192, 32, 4);

  // down: out = h@Wd^T + lora (fp32)
  k_gemm<<<64 * 16, 256, 0, stream>>>(gbuf, Wdb, ha, BdT, (const u16*)nullptr,
                                      out, 2048, 5504, 2);
}

// Round 3
// 886.228 us; speedup vs baseline: 1.5788x; 1.1432x over previous
//
#include <hip/hip_runtime.h>
#include <stdint.h>

typedef unsigned short u16;
typedef __bf16 bf16x8 __attribute__((ext_vector_type(8)));
typedef float f32x4 __attribute__((ext_vector_type(4)));

#define AS1 __attribute__((address_space(1)))
#define AS3 __attribute__((address_space(3)))

__device__ __forceinline__ void g2l16(const void* g, void* l) {
  __builtin_amdgcn_global_load_lds((AS1 void*)(void*)g, (AS3 void*)l, 16, 0, 0);
}

__device__ __forceinline__ u16 f2bf(float f) {
  union { float f; uint32_t u; } v; v.f = f;
  return (u16)((v.u + 0x7fffu + ((v.u >> 16) & 1u)) >> 16);
}
__device__ __forceinline__ float bf2f(u16 b) {
  union { uint32_t u; float f; } v; v.u = ((uint32_t)b) << 16;
  return v.f;
}

// ---- top-2 expert selection per batch (B=4, E=8) ----
__global__ void k_top2(const float* __restrict__ gv, int* __restrict__ idx) {
  int b = threadIdx.x;
  if (b < 4) {
    const float* g = gv + b * 8;
    int i1 = 0; float v1 = g[0];
    for (int e = 1; e < 8; ++e) if (g[e] > v1) { v1 = g[e]; i1 = e; }
    int i2 = -1; float v2 = -3.0e38f;
    for (int e = 0; e < 8; ++e) if (e != i1 && g[e] > v2) { v2 = g[e]; i2 = e; }
    idx[2 * b] = i1; idx[2 * b + 1] = i2;
  }
}

// ---- fp32 -> bf16 cast, vectorized ----
__global__ void k_cast(const float* __restrict__ in, u16* __restrict__ out, int n4) {
  int i = blockIdx.x * 256 + threadIdx.x;
  if (i < n4) {
    float4 v = ((const float4*)in)[i];
    ushort4 o = make_ushort4(f2bf(v.x), f2bf(v.y), f2bf(v.z), f2bf(v.w));
    ((ushort4*)out)[i] = o;
  }
}

// ---- per-batch A^T panels: out[b][j][k] = src[e][k][r], bf16 ----
__global__ void k_aT(const float* __restrict__ A0, const float* __restrict__ A1,
                     const int* __restrict__ idx, u16* __restrict__ out,
                     int Kd, int jmax) {
  int t = blockIdx.x * 256 + threadIdx.x;
  if (t >= 4 * jmax * Kd) return;
  int h = t % Kd;
  int j = (t / Kd) % jmax;
  int b = t / (Kd * jmax);
  const float* src = (j >= 32) ? A1 : A0;
  int jj = j & 31;
  int e = idx[2 * b + ((jj >> 4) & 1)];
  int r = jj & 15;
  out[t] = f2bf(src[((size_t)e * Kd + h) * 16 + r]);
}

// ---- build per-batch B_cat^T: out[b][n][j] = B[e(b, j>=16)][j&15][n], bf16 ----
__global__ void k_bT(const float* __restrict__ Bsrc, const int* __restrict__ idx,
                     u16* __restrict__ out, int N) {
  int t = blockIdx.x * 256 + threadIdx.x;
  if (t < 4 * N * 32) {
    int j = t & 31;
    int n = (t >> 5) % N;
    int b = t / (N * 32);
    int e = (j & 16) ? idx[2 * b + 1] : idx[2 * b];
    int r = j & 15;
    out[t] = f2bf(Bsrc[((size_t)e * 16 + r) * N + n]);
  }
}

// ---- skinny MFMA GEMM with split-K ----
template <int N2>
__global__ __launch_bounds__(256) void k_skinny(
    const u16* __restrict__ A, const u16* __restrict__ BT,
    float* __restrict__ part, int M, int K, int total_iters, int iters_per_chunk) {
  __shared__ u16 sA[128 * 64];
  __shared__ u16 sB[N2 * 64];
  int nm = M >> 7;
  int bm = blockIdx.x % nm, chunk = blockIdx.x / nm;
  int m0 = bm << 7;
  int batch = m0 >> 11;
  int tid = threadIdx.x, lane = tid & 63, w = tid >> 6;
  int kb = chunk * iters_per_chunk;
  int ke = min(total_iters, kb + iters_per_chunk);

  const u16* Bb = BT + (size_t)batch * N2 * K;

  const u16* ga[4]; u16* la[4];
  #pragma unroll
  for (int t = 0; t < 4; ++t) {
    int cb = 4 * w + t;
    int q = cb * 64 + lane;
    int row = q >> 3;
    int c = (q & 7) ^ (row & 7);
    ga[t] = A + (size_t)(m0 + row) * K + (size_t)kb * 64 + c * 8;
    la[t] = sA + cb * 512;
  }
  constexpr int nB = N2 / 32;
  const u16* gb[nB]; u16* lb[nB];
  #pragma unroll
  for (int t = 0; t < nB; ++t) {
    int cb = nB * w + t;
    int q = cb * 64 + lane;
    int row = q >> 3;
    int c = (q & 7) ^ (row & 7);
    gb[t] = Bb + (size_t)row * K + (size_t)kb * 64 + c * 8;
    lb[t] = sB + cb * 512;
  }

  f32x4 acc[2][N2 / 16] = {};
  for (int kt = kb; kt < ke; ++kt) {
    #pragma unroll
    for (int t = 0; t < 4; ++t) { g2l16(ga[t], la[t]); ga[t] += 64; }
    #pragma unroll
    for (int t = 0; t < nB; ++t) { g2l16(gb[t], lb[t]); gb[t] += 64; }
    __syncthreads();
    #pragma unroll
    for (int ks = 0; ks < 2; ++ks) {
      int cb0 = ks * 4 + (lane >> 4);
      bf16x8 af[2], bfr[N2 / 16];
      #pragma unroll
      for (int mi = 0; mi < 2; ++mi) {
        int row = 32 * w + mi * 16 + (lane & 15);
        af[mi] = *(const bf16x8*)(sA + (row * 8 + (cb0 ^ (row & 7))) * 8);
      }
      #pragma unroll
      for (int ni = 0; ni < N2 / 16; ++ni) {
        int row = ni * 16 + (lane & 15);
        bfr[ni] = *(const bf16x8*)(sB + (row * 8 + (cb0 ^ (row & 7))) * 8);
      }
      #pragma unroll
      for (int mi = 0; mi < 2; ++mi)
        #pragma unroll
        for (int ni = 0; ni < N2 / 16; ++ni)
          acc[mi][ni] = __builtin_amdgcn_mfma_f32_16x16x32_bf16(
              af[mi], bfr[ni], acc[mi][ni], 0, 0, 0);
    }
    __syncthreads();
  }

  int rb = (lane >> 4) * 4, cc = lane & 15;
  #pragma unroll
  for (int mi = 0; mi < 2; ++mi)
    #pragma unroll
    for (int ni = 0; ni < N2 / 16; ++ni)
      #pragma unroll
      for (int reg = 0; reg < 4; ++reg) {
        int gr = m0 + 32 * w + mi * 16 + rb + reg;
        int gc = ni * 16 + cc;
        part[((size_t)chunk * M + gr) * N2 + gc] = acc[mi][ni][reg];
      }
}

// ---- finalize split-K: out = bf16(2 * sum_chunks part) ----
__global__ void k_fin(const float* __restrict__ part, u16* __restrict__ out0,
                      u16* __restrict__ out1, int M, int N2, int nch) {
  int t = blockIdx.x * 256 + threadIdx.x;
  if (t >= M * N2) return;
  float s = 0.f;
  for (int c = 0; c < nch; ++c) s += part[(size_t)c * M * N2 + t];
  int j = t % N2, bs = t / N2;
  u16 v = f2bf(2.0f * s);
  if (N2 == 64) {
    if (j < 32) out0[(size_t)bs * 32 + j] = v;
    else        out1[(size_t)bs * 32 + (j - 32)] = v;
  } else {
    out0[(size_t)bs * 32 + j] = v;
  }
}

// ---- main GEMM with XCD-aware L2 swizzle ----
// block->XCD is round-robin (blockIdx % 8). Each XCD owns an 8-strip bm band
// (A band = 4 MB, hottest data -> L2-resident); bn is the outer within-XCD
// coordinate so each B strip is fetched ~once per XCD and consumed by the 8
// co-resident band blocks. Requires gridDim.x % (8*nt) == 0 and nm % 8 == 0.
__global__ __launch_bounds__(256, 3)
void k_gemm(const u16* __restrict__ A, const u16* __restrict__ Bm,
            const u16* __restrict__ A2, const u16* __restrict__ B2,
            const u16* Gprev, void* Out,
            int N, int K, int mode) {
  __shared__ u16 sA[128 * 64];
  __shared__ u16 sB[128 * 64];
  int nt = N >> 7;
  int nm = gridDim.x / nt;
  int perx = nm >> 3;                 // bm strips per XCD
  int xcd = blockIdx.x & 7;
  int v = blockIdx.x >> 3;            // within-XCD linear index
  int bn = v / perx;
  int bm = xcd * perx + (v - bn * perx);
  int m0 = bm << 7, n0 = bn << 7;
  int tid = threadIdx.x, lane = tid & 63, w = tid >> 6;
  int mo = (w & 1) << 6, no = (w >> 1) << 6;

  const u16* ga[4]; const u16* gb[4];
  u16* la[4]; u16* lb[4];
  #pragma unroll
  for (int t = 0; t < 4; ++t) {
    int cb = 4 * w + t;
    int q = cb * 64 + lane;
    int row = q >> 3;
    int c = (q & 7) ^ (row & 7);
    ga[t] = A + (size_t)(m0 + row) * K + c * 8;
    gb[t] = Bm + (size_t)(n0 + row) * K + c * 8;
    la[t] = sA + cb * 512;
    lb[t] = sB + cb * 512;
  }

  f32x4 acc[4][4] = {};

  int kiters = K >> 6;
  for (int kt = 0; kt < kiters; ++kt) {
    #pragma unroll
    for (int t = 0; t < 4; ++t) { g2l16(ga[t], la[t]); ga[t] += 64; }
    #pragma unroll
    for (int t = 0; t < 4; ++t) { g2l16(gb[t], lb[t]); gb[t] += 64; }
    __syncthreads();
    #pragma unroll
    for (int ks = 0; ks < 2; ++ks) {
      bf16x8 af[4], bfr[4];
      int cb0 = ks * 4 + (lane >> 4);
      #pragma unroll
      for (int mi = 0; mi < 4; ++mi) {
        int row = mo + mi * 16 + (lane & 15);
        af[mi] = *(const bf16x8*)(sA + (row * 8 + (cb0 ^ (row & 7))) * 8);
      }
      #pragma unroll
      for (int ni = 0; ni < 4; ++ni) {
        int row = no + ni * 16 + (lane & 15);
        bfr[ni] = *(const bf16x8*)(sB + (row * 8 + (cb0 ^ (row & 7))) * 8);
      }
      #pragma unroll
      for (int mi = 0; mi < 4; ++mi)
        #pragma unroll
        for (int ni = 0; ni < 4; ++ni)
          acc[mi][ni] = __builtin_amdgcn_mfma_f32_16x16x32_bf16(
              af[mi], bfr[ni], acc[mi][ni], 0, 0, 0);
    }
    __syncthreads();
  }

  // LoRA extra K=32 step
  {
    int batch = m0 >> 11;
    const u16* B2b = B2 + (size_t)batch * N * 32;
    #pragma unroll
    for (int t = 0; t < 2; ++t) {
      int cb = 2 * w + t;
      int q = cb * 64 + lane;
      int row = q >> 2;
      int c = (q & 3) ^ (row & 3);
      g2l16(A2 + (size_t)(m0 + row) * 32 + c * 8, sA + cb * 512);
      g2l16(B2b + (size_t)(n0 + row) * 32 + c * 8, sB + cb * 512);
    }
    __syncthreads();
    bf16x8 af[4], bfr[4];
    int c0 = lane >> 4;
    #pragma unroll
    for (int mi = 0; mi < 4; ++mi) {
      int row = mo + mi * 16 + (lane & 15);
      af[mi] = *(const bf16x8*)(sA + (row * 4 + (c0 ^ (row & 3))) * 8);
    }
    #pragma unroll
    for (int ni = 0; ni < 4; ++ni) {
      int row = no + ni * 16 + (lane & 15);
      bfr[ni] = *(const bf16x8*)(sB + (row * 4 + (c0 ^ (row & 3))) * 8);
    }
    #pragma unroll
    for (int mi = 0; mi < 4; ++mi)
      #pragma unroll
      for (int ni = 0; ni < 4; ++ni)
        acc[mi][ni] = __builtin_amdgcn_mfma_f32_16x16x32_bf16(
            af[mi], bfr[ni], acc[mi][ni], 0, 0, 0);
  }

  int rb = (lane >> 4) * 4;
  int cc = lane & 15;
  #pragma unroll
  for (int mi = 0; mi < 4; ++mi) {
    #pragma unroll
    for (int ni = 0; ni < 4; ++ni) {
      #pragma unroll
      for (int reg = 0; reg < 4; ++reg) {
        int gr = m0 + mo + mi * 16 + rb + reg;
        int gc = n0 + no + ni * 16 + cc;
        size_t pos = (size_t)gr * N + gc;
        float v = acc[mi][ni][reg];
        if (mode == 0) {
          v = v / (1.f + __expf(-v));
          ((u16*)Out)[pos] = f2bf(v);
        } else if (mode == 1) {
          float g = bf2f(Gprev[pos]);
          ((u16*)Out)[pos] = f2bf(g * v);
        } else {
          ((float*)Out)[pos] = v;
        }
      }
    }
  }
}

extern "C" void kernel_launch(void* const* d_in, const int* in_sizes, int n_in,
                              void* d_out, int out_size, void* d_ws, size_t ws_size,
                              hipStream_t stream) {
  const float* x  = (const float*)d_in[0];
  const float* gv = (const float*)d_in[1];
  const float* Wg = (const float*)d_in[2];
  const float* Ag = (const float*)d_in[3];
  const float* Bg = (const float*)d_in[4];
  const float* Wu = (const float*)d_in[5];
  const float* Au = (const float*)d_in[6];
  const float* Bu = (const float*)d_in[7];
  const float* Wd = (const float*)d_in[8];
  const float* Ad = (const float*)d_in[9];
  const float* Bd = (const float*)d_in[10];
  float* out = (float*)d_out;

  char* ws = (char*)d_ws;
  size_t off = 0;
  auto alloc = [&](size_t bytes) -> void* {
    void* p = ws + off;
    off = (off + bytes + 255) & ~(size_t)255;
    return p;
  };
  int* idx  = (int*)alloc(32);
  u16* xb   = (u16*)alloc((size_t)8192 * 2048 * 2);
  u16* Wgb  = (u16*)alloc((size_t)5504 * 2048 * 2);
  u16* Wub  = (u16*)alloc((size_t)5504 * 2048 * 2);
  u16* Wdb  = (u16*)alloc((size_t)2048 * 5504 * 2);
  u16* xag  = (u16*)alloc((size_t)8192 * 32 * 2);
  u16* xau  = (u16*)alloc((size_t)8192 * 32 * 2);
  u16* ha   = (u16*)alloc((size_t)8192 * 32 * 2);
  u16* BgT  = (u16*)alloc((size_t)4 * 5504 * 32 * 2);
  u16* BuT  = (u16*)alloc((size_t)4 * 5504 * 32 * 2);
  u16* BdT  = (u16*)alloc((size_t)4 * 2048 * 32 * 2);
  u16* AxT  = (u16*)alloc((size_t)4 * 64 * 2048 * 2);
  u16* AdT  = (u16*)alloc((size_t)4 * 32 * 5504 * 2);
  u16* gbuf = (u16*)alloc((size_t)8192 * 5504 * 2);
  if (off > ws_size) return;

  float* part_xa = (float*)gbuf;   // dead region until gate GEMM
  float* part_ha = (float*)Wgb;    // dead region after gate GEMM

  k_top2<<<1, 64, 0, stream>>>(gv, idx);
  k_cast<<<16384, 256, 0, stream>>>(x, xb, 4194304);
  k_cast<<<11008, 256, 0, stream>>>(Wg, Wgb, 2818048);
  k_cast<<<11008, 256, 0, stream>>>(Wu, Wub, 2818048);
  k_cast<<<11008, 256, 0, stream>>>(Wd, Wdb, 2818048);
  k_aT<<<2048, 256, 0, stream>>>(Ag, Au, idx, AxT, 2048, 64);
  k_aT<<<2752, 256, 0, stream>>>(Ad, Ad, idx, AdT, 5504, 32);
  k_bT<<<2752, 256, 0, stream>>>(Bg, idx, BgT, 5504);
  k_bT<<<2752, 256, 0, stream>>>(Bu, idx, BuT, 5504);
  k_bT<<<1024, 256, 0, stream>>>(Bd, idx, BdT, 2048);

  // xa: [8192 x 64] = xb @ AxT^T, split-K 4 chunks (K=2048)
  k_skinny<64><<<64 * 4, 256, 0, stream>>>(xb, AxT, part_xa, 8192, 2048, 32, 8);
  k_fin<<<2048, 256, 0, stream>>>(part_xa, xag, xau, 8192, 64, 4);

  // gate: silu(x@Wg^T + lora) -> gbuf (bf16)
  k_gemm<<<64 * 43, 256, 0, stream>>>(xb, Wgb, xag, BgT, (const u16*)nullptr,
                                      gbuf, 5504, 2048, 0);
  // up: h = silu_gate * (x@Wu^T + lora) -> gbuf in place
  k_gemm<<<64 * 43, 256, 0, stream>>>(xb, Wub, xau, BuT, gbuf, gbuf, 5504, 2048, 1);

  // ha: [8192 x 32] = h @ AdT^T, split-K 4 chunks (K=5504)
  k_skinny<32><<<64 * 4, 256, 0, stream>>>(gbuf, AdT, part_ha, 8192, 5504, 86, 22);
  k_fin<<<1024, 256, 0, stream>>>(part_ha, ha, ha, 8192, 32, 4);

  // down: out = h@Wd^T + lora (fp32)
  k_gemm<<<64 * 16, 256, 0, stream>>>(gbuf, Wdb, ha, BdT, (const u16*)nullptr,
                                      out, 2048, 5504, 2);
}